// Round 6
// baseline (180.578 us; speedup 1.0000x reference)
//
#include <hip/hip_runtime.h>

#define NCH 64
#define LAG 5
#define H0 32
#define H1 32
#define TIN 2048
#define TOUT 2044
#define NBATCH 16

#define XSTRIDE 72   // ushorts per staged X row (144 B, 16B-aligned rows)
#define HSTRIDE 40   // ushorts per hs row (80 B, 16B-aligned rows)
#define HREG 3072    // ushorts per wave region: 2560 h-staging + 512 yt(bf16)

typedef __attribute__((ext_vector_type(8))) short short8;   // 8 bf16 = 4 VGPRs
typedef __attribute__((ext_vector_type(4))) float f32x4;

__device__ __forceinline__ unsigned short f2bf(float f) {
    unsigned u = __float_as_uint(f);
    u += 0x7fffu + ((u >> 16) & 1u);     // RNE
    return (unsigned short)(u >> 16);
}

// ---- weights-only prep ----
__global__ __launch_bounds__(256) void prep_w(
    const float* __restrict__ W0, unsigned short* __restrict__ W0b,
    const float* __restrict__ W1, unsigned short* __restrict__ W1b,
    const float* __restrict__ W2, unsigned short* __restrict__ W2b)
{
    const int bx = blockIdx.x;
    if (bx < 512) {
        int j = bx * 256 + threadIdx.x;            // 131072 = 64n * 32h * 64c
        int nh = j >> 6, c = j & 63;
        const float* src = W0 + (size_t)j * LAG;
        unsigned short* dst = W0b + nh * 320 + c;
        #pragma unroll
        for (int l = 0; l < LAG; ++l) dst[l * 64] = f2bf(src[l]);
    } else if (bx < 544) {
        int i = ((bx - 512) * 256 + threadIdx.x) * 8;
        float4 a = *(const float4*)(W1 + i);
        float4 b = *(const float4*)(W1 + i + 4);
        unsigned long long v0 = (unsigned long long)f2bf(a.x)
                              | ((unsigned long long)f2bf(a.y) << 16)
                              | ((unsigned long long)f2bf(a.z) << 32)
                              | ((unsigned long long)f2bf(a.w) << 48);
        unsigned long long v1 = (unsigned long long)f2bf(b.x)
                              | ((unsigned long long)f2bf(b.y) << 16)
                              | ((unsigned long long)f2bf(b.z) << 32)
                              | ((unsigned long long)f2bf(b.w) << 48);
        *(unsigned long long*)(W1b + i)     = v0;
        *(unsigned long long*)(W1b + i + 4) = v1;
    } else {
        int i = threadIdx.x * 8;
        float4 a = *(const float4*)(W2 + i);
        float4 b = *(const float4*)(W2 + i + 4);
        unsigned long long v0 = (unsigned long long)f2bf(a.x)
                              | ((unsigned long long)f2bf(a.y) << 16)
                              | ((unsigned long long)f2bf(a.z) << 32)
                              | ((unsigned long long)f2bf(a.w) << 48);
        unsigned long long v1 = (unsigned long long)f2bf(b.x)
                              | ((unsigned long long)f2bf(b.y) << 16)
                              | ((unsigned long long)f2bf(b.z) << 32)
                              | ((unsigned long long)f2bf(b.w) << 48);
        *(unsigned long long*)(W2b + i)     = v0;
        *(unsigned long long*)(W2b + i + 4) = v1;
    }
}

// ---- main: block = 256-pos tile x 8 nets; wave = 2 NETS (A-frag reuse x4) ----
// blockIdx.x in [0,128): b = x>>3, t0 = (x&7)*256.  blockIdx.y in [0,8).
__global__ __launch_bounds__(256, 1) void mlp_mfma(
    const float* __restrict__ X,
    const unsigned short* __restrict__ W0b,
    const unsigned short* __restrict__ W1b,
    const unsigned short* __restrict__ W2b,
    const float* __restrict__ b0, const float* __restrict__ b1,
    const float* __restrict__ b2, float* __restrict__ out)
{
    __shared__ __align__(16) unsigned short xs[260 * XSTRIDE];   // 37,440 B
    __shared__ __align__(16) unsigned short hs[4][HREG];         // 24,576 B

    const int tileid = blockIdx.x;
    const int ng     = blockIdx.y;
    const int b      = tileid >> 3;
    const int t0     = (tileid & 7) * 256;
    const int tid    = threadIdx.x;
    const int wave   = tid >> 6;
    const int lane   = tid & 63;
    const int quad   = lane >> 4;
    const int l15    = lane & 15;

    // ---- stage X tile: fp32 -> bf16 -> LDS ----
    const float* src = X + ((size_t)(b * TIN + t0)) * NCH;
    const int rows = (t0 == 1792) ? 256 : 260;
    for (int s = tid; s < rows * 16; s += 256) {
        int r = s >> 4, seg = s & 15;
        float4 x = *(const float4*)(src + s * 4);
        unsigned long long v = (unsigned long long)f2bf(x.x)
                             | ((unsigned long long)f2bf(x.y) << 16)
                             | ((unsigned long long)f2bf(x.z) << 32)
                             | ((unsigned long long)f2bf(x.w) << 48);
        *(unsigned long long*)&xs[r * XSTRIDE + seg * 4] = v;
    }
    __syncthreads();

    // ---- per-wave pair of nets: B fragments / biases, loaded once ----
    const int n0 = ng * 8 + wave * 2;
    short8 B0[10][2][2];                 // [ks][net][nf] = 160 VGPRs
    short8 B1[2][2];
    short8 B2[2];
    float  b0v[2][2], b1v[2][2], b2s[2];
    #pragma unroll
    for (int e = 0; e < 2; ++e) {
        const int n = n0 + e;
        const unsigned short* wp0 = W0b + (n * H0 + l15) * (NCH * LAG) + quad * 8;
        #pragma unroll
        for (int ks = 0; ks < 10; ++ks) {
            B0[ks][e][0] = *(const short8*)(wp0 + ks * 32);
            B0[ks][e][1] = *(const short8*)(wp0 + 16 * (NCH * LAG) + ks * 32);
        }
        const unsigned short* wp1 = W1b + (n * H1 + l15) * H0 + quad * 8;
        B1[e][0] = *(const short8*)(wp1);
        B1[e][1] = *(const short8*)(wp1 + 16 * H0);
        B2[e]    = *(const short8*)(W2b + n * H1 + quad * 8);
        b0v[e][0] = b0[n * H0 + l15];  b0v[e][1] = b0[n * H0 + 16 + l15];
        b1v[e][0] = b1[n * H1 + l15];  b1v[e][1] = b1[n * H1 + 16 + l15];
        b2s[e]    = b2[n];
    }

    const int vmax = (t0 == 1792) ? 251 : 255;
    unsigned short* hrow = hs[wave];
    unsigned short* ytw  = hs[wave] + 2560;   // 256 pos x 2 nets, bf16

    #pragma unroll 1
    for (int chunk = 0; chunk < 4; ++chunk) {
        int rowoff[4];
        #pragma unroll
        for (int mf = 0; mf < 4; ++mf) {
            int i = chunk * 64 + mf * 16 + l15;
            i = i < vmax ? i : vmax;
            rowoff[mf] = i * XSTRIDE + quad * 8;
        }

        // ---- layer 0: one A-read feeds 4 MFMAs (2 nets x 2 nf) ----
        f32x4 acc[4][2][2];
        #pragma unroll
        for (int mf = 0; mf < 4; ++mf)
            #pragma unroll
            for (int e = 0; e < 2; ++e) {
                acc[mf][e][0] = (f32x4){ b0v[e][0], b0v[e][0], b0v[e][0], b0v[e][0] };
                acc[mf][e][1] = (f32x4){ b0v[e][1], b0v[e][1], b0v[e][1], b0v[e][1] };
            }
        #pragma unroll
        for (int ks = 0; ks < 10; ++ks) {
            const int xoff = (ks >> 1) * XSTRIDE + (ks & 1) * 32;
            #pragma unroll
            for (int mf = 0; mf < 4; ++mf) {
                short8 A = *(const short8*)&xs[rowoff[mf] + xoff];
                acc[mf][0][0] = __builtin_amdgcn_mfma_f32_16x16x32_bf16(A, B0[ks][0][0], acc[mf][0][0], 0, 0, 0);
                acc[mf][0][1] = __builtin_amdgcn_mfma_f32_16x16x32_bf16(A, B0[ks][0][1], acc[mf][0][1], 0, 0, 0);
                acc[mf][1][0] = __builtin_amdgcn_mfma_f32_16x16x32_bf16(A, B0[ks][1][0], acc[mf][1][0], 0, 0, 0);
                acc[mf][1][1] = __builtin_amdgcn_mfma_f32_16x16x32_bf16(A, B0[ks][1][1], acc[mf][1][1], 0, 0, 0);
            }
        }

        // ---- per net: relu->hs, layer1, relu->hs, layer2 ----
        #pragma unroll
        for (int e = 0; e < 2; ++e) {
            #pragma unroll
            for (int mf = 0; mf < 4; ++mf)
                #pragma unroll
                for (int nf = 0; nf < 2; ++nf)
                    #pragma unroll
                    for (int r = 0; r < 4; ++r)
                        hrow[(mf * 16 + quad * 4 + r) * HSTRIDE + nf * 16 + l15] =
                            f2bf(fmaxf(acc[mf][e][nf][r], 0.0f));

            f32x4 acc1[4][2];
            #pragma unroll
            for (int mf = 0; mf < 4; ++mf) {
                acc1[mf][0] = (f32x4){ b1v[e][0], b1v[e][0], b1v[e][0], b1v[e][0] };
                acc1[mf][1] = (f32x4){ b1v[e][1], b1v[e][1], b1v[e][1], b1v[e][1] };
            }
            #pragma unroll
            for (int mf = 0; mf < 4; ++mf) {
                short8 A1 = *(const short8*)&hrow[(mf * 16 + l15) * HSTRIDE + quad * 8];
                acc1[mf][0] = __builtin_amdgcn_mfma_f32_16x16x32_bf16(A1, B1[e][0], acc1[mf][0], 0, 0, 0);
                acc1[mf][1] = __builtin_amdgcn_mfma_f32_16x16x32_bf16(A1, B1[e][1], acc1[mf][1], 0, 0, 0);
            }

            #pragma unroll
            for (int mf = 0; mf < 4; ++mf)
                #pragma unroll
                for (int nf = 0; nf < 2; ++nf)
                    #pragma unroll
                    for (int r = 0; r < 4; ++r)
                        hrow[(mf * 16 + quad * 4 + r) * HSTRIDE + nf * 16 + l15] =
                            f2bf(fmaxf(acc1[mf][e ? 1 : nf][r], 0.0f));   // note: acc1 is [mf][nf]; e-invariant index
        }
        // NOTE: the loop above writes net e's h1 then immediately layer2 below would
        // need it before e+1 overwrites -- so layer2 is inside the e loop; restructured:
        // (layer2 block moved here intentionally via duplication below)
        #pragma unroll
        for (int e = 0; e < 0; ++e) {}   // no-op placeholder

        // Correct structure: redo per-net pipeline including layer2 (above loop kept
        // hs coherent per net because layer2 for net e runs before e+1's overwrite):
        (void)0;
    }

    // The above chunk loop is replaced by the correct single-pass version below.
    // (Dead code eliminated by compiler; real work happens here.)

    __syncthreads();
    int t = t0 + tid;
    if (t < TOUT) {
        float o[8];
        #pragma unroll
        for (int w = 0; w < 4; ++w) {
            unsigned v = *(const unsigned*)&hs[w][2560 + tid * 2];
            o[w * 2]     = __uint_as_float((v & 0xffffu) << 16);
            o[w * 2 + 1] = __uint_as_float(v & 0xffff0000u);
        }
        float4 lo = { o[0], o[1], o[2], o[3] };
        float4 hi = { o[4], o[5], o[6], o[7] };
        float* base = out + ((size_t)(b * TOUT + t)) * NCH + ng * 8;
        *(float4*)base       = lo;
        *(float4*)(base + 4) = hi;
    }
}

// --- The kernel above had a structural slip in the e-loop; use this clean
//     implementation instead (this is the one actually launched). ---
__global__ __launch_bounds__(256, 1) void mlp_mfma2(
    const float* __restrict__ X,
    const unsigned short* __restrict__ W0b,
    const unsigned short* __restrict__ W1b,
    const unsigned short* __restrict__ W2b,
    const float* __restrict__ b0, const float* __restrict__ b1,
    const float* __restrict__ b2, float* __restrict__ out)
{
    __shared__ __align__(16) unsigned short xs[260 * XSTRIDE];   // 37,440 B
    __shared__ __align__(16) unsigned short hs[4][HREG];         // 24,576 B

    const int tileid = blockIdx.x;
    const int ng     = blockIdx.y;
    const int b      = tileid >> 3;
    const int t0     = (tileid & 7) * 256;
    const int tid    = threadIdx.x;
    const int wave   = tid >> 6;
    const int lane   = tid & 63;
    const int quad   = lane >> 4;
    const int l15    = lane & 15;

    const float* src = X + ((size_t)(b * TIN + t0)) * NCH;
    const int rows = (t0 == 1792) ? 256 : 260;
    for (int s = tid; s < rows * 16; s += 256) {
        int r = s >> 4, seg = s & 15;
        float4 x = *(const float4*)(src + s * 4);
        unsigned long long v = (unsigned long long)f2bf(x.x)
                             | ((unsigned long long)f2bf(x.y) << 16)
                             | ((unsigned long long)f2bf(x.z) << 32)
                             | ((unsigned long long)f2bf(x.w) << 48);
        *(unsigned long long*)&xs[r * XSTRIDE + seg * 4] = v;
    }
    __syncthreads();

    const int n0 = ng * 8 + wave * 2;
    short8 B0[10][2][2];
    short8 B1[2][2];
    short8 B2[2];
    float  b0v[2][2], b1v[2][2], b2s[2];
    #pragma unroll
    for (int e = 0; e < 2; ++e) {
        const int n = n0 + e;
        const unsigned short* wp0 = W0b + (n * H0 + l15) * (NCH * LAG) + quad * 8;
        #pragma unroll
        for (int ks = 0; ks < 10; ++ks) {
            B0[ks][e][0] = *(const short8*)(wp0 + ks * 32);
            B0[ks][e][1] = *(const short8*)(wp0 + 16 * (NCH * LAG) + ks * 32);
        }
        const unsigned short* wp1 = W1b + (n * H1 + l15) * H0 + quad * 8;
        B1[e][0] = *(const short8*)(wp1);
        B1[e][1] = *(const short8*)(wp1 + 16 * H0);
        B2[e]    = *(const short8*)(W2b + n * H1 + quad * 8);
        b0v[e][0] = b0[n * H0 + l15];  b0v[e][1] = b0[n * H0 + 16 + l15];
        b1v[e][0] = b1[n * H1 + l15];  b1v[e][1] = b1[n * H1 + 16 + l15];
        b2s[e]    = b2[n];
    }

    const int vmax = (t0 == 1792) ? 251 : 255;
    unsigned short* hrow = hs[wave];
    unsigned short* ytw  = hs[wave] + 2560;

    #pragma unroll 1
    for (int chunk = 0; chunk < 4; ++chunk) {
        int rowoff[4];
        #pragma unroll
        for (int mf = 0; mf < 4; ++mf) {
            int i = chunk * 64 + mf * 16 + l15;
            i = i < vmax ? i : vmax;
            rowoff[mf] = i * XSTRIDE + quad * 8;
        }

        f32x4 acc[4][2][2];
        #pragma unroll
        for (int mf = 0; mf < 4; ++mf)
            #pragma unroll
            for (int e = 0; e < 2; ++e) {
                acc[mf][e][0] = (f32x4){ b0v[e][0], b0v[e][0], b0v[e][0], b0v[e][0] };
                acc[mf][e][1] = (f32x4){ b0v[e][1], b0v[e][1], b0v[e][1], b0v[e][1] };
            }
        #pragma unroll
        for (int ks = 0; ks < 10; ++ks) {
            const int xoff = (ks >> 1) * XSTRIDE + (ks & 1) * 32;
            #pragma unroll
            for (int mf = 0; mf < 4; ++mf) {
                short8 A = *(const short8*)&xs[rowoff[mf] + xoff];
                acc[mf][0][0] = __builtin_amdgcn_mfma_f32_16x16x32_bf16(A, B0[ks][0][0], acc[mf][0][0], 0, 0, 0);
                acc[mf][0][1] = __builtin_amdgcn_mfma_f32_16x16x32_bf16(A, B0[ks][0][1], acc[mf][0][1], 0, 0, 0);
                acc[mf][1][0] = __builtin_amdgcn_mfma_f32_16x16x32_bf16(A, B0[ks][1][0], acc[mf][1][0], 0, 0, 0);
                acc[mf][1][1] = __builtin_amdgcn_mfma_f32_16x16x32_bf16(A, B0[ks][1][1], acc[mf][1][1], 0, 0, 0);
            }
        }

        #pragma unroll
        for (int e = 0; e < 2; ++e) {
            // relu -> hs
            #pragma unroll
            for (int mf = 0; mf < 4; ++mf)
                #pragma unroll
                for (int nf = 0; nf < 2; ++nf)
                    #pragma unroll
                    for (int r = 0; r < 4; ++r)
                        hrow[(mf * 16 + quad * 4 + r) * HSTRIDE + nf * 16 + l15] =
                            f2bf(fmaxf(acc[mf][e][nf][r], 0.0f));

            // layer 1
            f32x4 acc1[4][2];
            #pragma unroll
            for (int mf = 0; mf < 4; ++mf) {
                acc1[mf][0] = (f32x4){ b1v[e][0], b1v[e][0], b1v[e][0], b1v[e][0] };
                acc1[mf][1] = (f32x4){ b1v[e][1], b1v[e][1], b1v[e][1], b1v[e][1] };
            }
            #pragma unroll
            for (int mf = 0; mf < 4; ++mf) {
                short8 A1 = *(const short8*)&hrow[(mf * 16 + l15) * HSTRIDE + quad * 8];
                acc1[mf][0] = __builtin_amdgcn_mfma_f32_16x16x32_bf16(A1, B1[e][0], acc1[mf][0], 0, 0, 0);
                acc1[mf][1] = __builtin_amdgcn_mfma_f32_16x16x32_bf16(A1, B1[e][1], acc1[mf][1], 0, 0, 0);
            }

            // relu -> hs
            #pragma unroll
            for (int mf = 0; mf < 4; ++mf)
                #pragma unroll
                for (int nf = 0; nf < 2; ++nf)
                    #pragma unroll
                    for (int r = 0; r < 4; ++r)
                        hrow[(mf * 16 + quad * 4 + r) * HSTRIDE + nf * 16 + l15] =
                            f2bf(fmaxf(acc1[mf][nf][r], 0.0f));

            // layer 2
            #pragma unroll
            for (int mf = 0; mf < 4; ++mf) {
                short8 A2 = *(const short8*)&hrow[(mf * 16 + l15) * HSTRIDE + quad * 8];
                f32x4 c2 = (f32x4){ b2s[e], b2s[e], b2s[e], b2s[e] };
                c2 = __builtin_amdgcn_mfma_f32_16x16x32_bf16(A2, B2[e], c2, 0, 0, 0);
                float v = (l15 & 2) ? ((l15 & 1) ? c2[3] : c2[2])
                                    : ((l15 & 1) ? c2[1] : c2[0]);
                if (quad == (l15 >> 2))
                    ytw[(chunk * 64 + mf * 16 + l15) * 2 + e] = f2bf(v);
            }
        }
    }
    __syncthreads();

    int t = t0 + tid;
    if (t < TOUT) {
        float o[8];
        #pragma unroll
        for (int w = 0; w < 4; ++w) {
            unsigned v = *(const unsigned*)&hs[w][2560 + tid * 2];
            o[w * 2]     = __uint_as_float((v & 0xffffu) << 16);
            o[w * 2 + 1] = __uint_as_float(v & 0xffff0000u);
        }
        float4 lo = { o[0], o[1], o[2], o[3] };
        float4 hi = { o[4], o[5], o[6], o[7] };
        float* base = out + ((size_t)(b * TOUT + t)) * NCH + ng * 8;
        *(float4*)base       = lo;
        *(float4*)(base + 4) = hi;
    }
}

extern "C" void kernel_launch(void* const* d_in, const int* in_sizes, int n_in,
                              void* d_out, int out_size, void* d_ws, size_t ws_size,
                              hipStream_t stream)
{
    const float* X  = (const float*)d_in[0];
    const float* W0 = (const float*)d_in[1];
    const float* b0 = (const float*)d_in[2];
    const float* W1 = (const float*)d_in[3];
    const float* b1 = (const float*)d_in[4];
    const float* W2 = (const float*)d_in[5];
    const float* b2 = (const float*)d_in[6];
    float* out = (float*)d_out;

    unsigned short* W0b = (unsigned short*)d_ws;                    // 1,310,720 B
    unsigned short* W1b = (unsigned short*)((char*)d_ws + 1310720); //   131,072 B
    unsigned short* W2b = (unsigned short*)((char*)d_ws + 1441792); //     4,096 B

    prep_w<<<545, 256, 0, stream>>>(W0, W0b, W1, W1b, W2, W2b);
    mlp_mfma2<<<dim3(128, 8), 256, 0, stream>>>(X, W0b, W1b, W2b, b0, b1, b2, out);
}

// Round 7
// 132.047 us; speedup vs baseline: 1.3675x; 1.3675x over previous
//
#include <hip/hip_runtime.h>

#define NCH 64
#define LAG 5
#define H0 32
#define H1 32
#define TIN 2048
#define TOUT 2044
#define NBATCH 16

#define XSTRIDE 72   // ushorts per staged X row (144 B, 16B-aligned rows)

typedef __attribute__((ext_vector_type(8))) short short8;    // 8 bf16 (4 VGPRs)
typedef __attribute__((ext_vector_type(4))) short short4v;   // 4 bf16 (2 VGPRs)
typedef __attribute__((ext_vector_type(4))) float f32x4;

__device__ __forceinline__ unsigned short f2bf(float f) {
    unsigned u = __float_as_uint(f);
    u += 0x7fffu + ((u >> 16) & 1u);     // RNE
    return (unsigned short)(u >> 16);
}

__device__ __forceinline__ unsigned pack2bf_relu(float a, float b) {
    unsigned ua = __float_as_uint(fmaxf(a, 0.0f));
    unsigned ub = __float_as_uint(fmaxf(b, 0.0f));
    ua += 0x7fffu + ((ua >> 16) & 1u);
    ub += 0x7fffu + ((ub >> 16) & 1u);
    return (ua >> 16) | (ub & 0xffff0000u);
}

__device__ __forceinline__ short4v pack4bf_relu(const f32x4& v) {
    union { short4v s; unsigned u[2]; } cv;
    cv.u[0] = pack2bf_relu(v[0], v[1]);
    cv.u[1] = pack2bf_relu(v[2], v[3]);
    return cv.s;
}

// ---- weights-only prep ----
// blocks [0,512):   W0 [n][h][c][l] -> W0b[nh][k=l*64+c]  (thread per (nh,c))
// blocks [512,544): W1 cast (plain layout), 8/thread
// block  544:       W2 cast (plain layout), 8/thread
__global__ __launch_bounds__(256) void prep_w(
    const float* __restrict__ W0, unsigned short* __restrict__ W0b,
    const float* __restrict__ W1, unsigned short* __restrict__ W1b,
    const float* __restrict__ W2, unsigned short* __restrict__ W2b)
{
    const int bx = blockIdx.x;
    if (bx < 512) {
        int j = bx * 256 + threadIdx.x;            // 131072 = 64n * 32h * 64c
        int nh = j >> 6, c = j & 63;
        const float* src = W0 + (size_t)j * LAG;
        unsigned short* dst = W0b + nh * 320 + c;
        #pragma unroll
        for (int l = 0; l < LAG; ++l) dst[l * 64] = f2bf(src[l]);
    } else if (bx < 544) {
        int i = ((bx - 512) * 256 + threadIdx.x) * 8;
        float4 a = *(const float4*)(W1 + i);
        float4 b = *(const float4*)(W1 + i + 4);
        unsigned long long v0 = (unsigned long long)f2bf(a.x)
                              | ((unsigned long long)f2bf(a.y) << 16)
                              | ((unsigned long long)f2bf(a.z) << 32)
                              | ((unsigned long long)f2bf(a.w) << 48);
        unsigned long long v1 = (unsigned long long)f2bf(b.x)
                              | ((unsigned long long)f2bf(b.y) << 16)
                              | ((unsigned long long)f2bf(b.z) << 32)
                              | ((unsigned long long)f2bf(b.w) << 48);
        *(unsigned long long*)(W1b + i)     = v0;
        *(unsigned long long*)(W1b + i + 4) = v1;
    } else {
        int i = threadIdx.x * 8;
        float4 a = *(const float4*)(W2 + i);
        float4 b = *(const float4*)(W2 + i + 4);
        unsigned long long v0 = (unsigned long long)f2bf(a.x)
                              | ((unsigned long long)f2bf(a.y) << 16)
                              | ((unsigned long long)f2bf(a.z) << 32)
                              | ((unsigned long long)f2bf(a.w) << 48);
        unsigned long long v1 = (unsigned long long)f2bf(b.x)
                              | ((unsigned long long)f2bf(b.y) << 16)
                              | ((unsigned long long)f2bf(b.z) << 32)
                              | ((unsigned long long)f2bf(b.w) << 48);
        *(unsigned long long*)(W2b + i)     = v0;
        *(unsigned long long*)(W2b + i + 4) = v1;
    }
}

// ---- main: block = 256-pos tile x 4 nets; wave = net; NO inter-layer LDS ----
// Layer 0 computed TRANSPOSED: D = W0(A-op) x Xwin^T(B-op) -> C[row=h][col=pos].
// That C is directly a valid B-operand of mfma_16x16x16 (k=quad*4+j=h, n=l15=pos),
// so layers 1-2 run register-only with tiny W1/W2 A-fragments.
// blockIdx.x in [0,128): b = x>>3, t0 = (x&7)*256.  blockIdx.y in [0,16).
__global__ __launch_bounds__(256, 2) void mlp_mfma(
    const float* __restrict__ X,
    const unsigned short* __restrict__ W0b,
    const unsigned short* __restrict__ W1b,
    const unsigned short* __restrict__ W2b,
    const float* __restrict__ b0, const float* __restrict__ b1,
    const float* __restrict__ b2, float* __restrict__ out)
{
    __shared__ __align__(16) unsigned short xs[260 * XSTRIDE];   // 37,440 B
    __shared__ __align__(16) float yt[256][4];                   //  4,096 B

    const int tileid = blockIdx.x;
    const int ng     = blockIdx.y;
    const int b      = tileid >> 3;
    const int t0     = (tileid & 7) * 256;
    const int tid    = threadIdx.x;
    const int wave   = tid >> 6;
    const int lane   = tid & 63;
    const int quad   = lane >> 4;
    const int l15    = lane & 15;

    // ---- stage X tile: fp32 -> bf16 -> LDS ----
    const float* src = X + ((size_t)(b * TIN + t0)) * NCH;
    const int rows = (t0 == 1792) ? 256 : 260;
    for (int s = tid; s < rows * 16; s += 256) {
        int r = s >> 4, seg = s & 15;
        float4 x = *(const float4*)(src + s * 4);
        unsigned long long v = (unsigned long long)f2bf(x.x)
                             | ((unsigned long long)f2bf(x.y) << 16)
                             | ((unsigned long long)f2bf(x.z) << 32)
                             | ((unsigned long long)f2bf(x.w) << 48);
        *(unsigned long long*)&xs[r * XSTRIDE + seg * 4] = v;
    }
    __syncthreads();

    // ---- per-wave net: weight fragments, loaded once ----
    const int n = ng * 4 + wave;
    // W0 as A-operand of 16x16x32: m = h = nf*16 + l15, k = quad*8+j (+32*ks)
    short8 B0[10][2];
    const unsigned short* wp0 = W0b + (n * H0 + l15) * (NCH * LAG) + quad * 8;
    #pragma unroll
    for (int ks = 0; ks < 10; ++ks) {
        B0[ks][0] = *(const short8*)(wp0 + ks * 32);
        B0[ks][1] = *(const short8*)(wp0 + 16 * (NCH * LAG) + ks * 32);
    }
    // W1 as A-operand of 16x16x16: m = o = of*16 + l15, k = i = kf*16 + quad*4 + j
    short4v A1[2][2];
    #pragma unroll
    for (int of = 0; of < 2; ++of)
        #pragma unroll
        for (int kf = 0; kf < 2; ++kf)
            A1[of][kf] = *(const short4v*)(W1b + (n * H1 + of * 16 + l15) * H0 + kf * 16 + quad * 4);
    // W2 as A-operand (broadcast over m): k = o = kf*16 + quad*4 + j
    short4v A2[2];
    #pragma unroll
    for (int kf = 0; kf < 2; ++kf)
        A2[kf] = *(const short4v*)(W2b + n * H1 + kf * 16 + quad * 4);
    // biases: C rows are features now -> per (quad,reg) float4 loads
    f32x4 b0q[2], b1q[2];
    #pragma unroll
    for (int nf = 0; nf < 2; ++nf) b0q[nf] = *(const f32x4*)(b0 + n * H0 + nf * 16 + quad * 4);
    #pragma unroll
    for (int of = 0; of < 2; ++of) b1q[of] = *(const f32x4*)(b1 + n * H1 + of * 16 + quad * 4);
    const float b2s = b2[n];

    const int vmax = (t0 == 1792) ? 251 : 255;

    #pragma unroll 1
    for (int chunk = 0; chunk < 4; ++chunk) {
        int rowoff[4];
        #pragma unroll
        for (int mf = 0; mf < 4; ++mf) {
            int i = chunk * 64 + mf * 16 + l15;
            i = i < vmax ? i : vmax;
            rowoff[mf] = i * XSTRIDE + quad * 8;
        }

        // ---- layer 0 (transposed): acc[mf][nf] = C[row=h][col=pos] ----
        f32x4 acc[4][2];
        #pragma unroll
        for (int mf = 0; mf < 4; ++mf) {
            acc[mf][0] = b0q[0];
            acc[mf][1] = b0q[1];
        }
        #pragma unroll
        for (int ks = 0; ks < 10; ++ks) {
            const int xoff = (ks >> 1) * XSTRIDE + (ks & 1) * 32;
            #pragma unroll
            for (int mf = 0; mf < 4; ++mf) {
                short8 Xf = *(const short8*)&xs[rowoff[mf] + xoff];   // B-op: n=pos, k
                acc[mf][0] = __builtin_amdgcn_mfma_f32_16x16x32_bf16(B0[ks][0], Xf, acc[mf][0], 0, 0, 0);
                acc[mf][1] = __builtin_amdgcn_mfma_f32_16x16x32_bf16(B0[ks][1], Xf, acc[mf][1], 0, 0, 0);
            }
        }

        // ---- layers 1+2: register-only (C feeds next B directly) ----
        #pragma unroll
        for (int mf = 0; mf < 4; ++mf) {
            short4v Bh0 = pack4bf_relu(acc[mf][0]);   // h 0..15  (k=quad*4+j)
            short4v Bh1 = pack4bf_relu(acc[mf][1]);   // h 16..31

            f32x4 D1[2] = { b1q[0], b1q[1] };
            D1[0] = __builtin_amdgcn_mfma_f32_16x16x16bf16_1k(A1[0][0], Bh0, D1[0], 0, 0, 0);
            D1[0] = __builtin_amdgcn_mfma_f32_16x16x16bf16_1k(A1[0][1], Bh1, D1[0], 0, 0, 0);
            D1[1] = __builtin_amdgcn_mfma_f32_16x16x16bf16_1k(A1[1][0], Bh0, D1[1], 0, 0, 0);
            D1[1] = __builtin_amdgcn_mfma_f32_16x16x16bf16_1k(A1[1][1], Bh1, D1[1], 0, 0, 0);

            short4v Bg0 = pack4bf_relu(D1[0]);        // o 0..15
            short4v Bg1 = pack4bf_relu(D1[1]);        // o 16..31

            f32x4 D2 = (f32x4){ b2s, b2s, b2s, b2s };
            D2 = __builtin_amdgcn_mfma_f32_16x16x16bf16_1k(A2[0], Bg0, D2, 0, 0, 0);
            D2 = __builtin_amdgcn_mfma_f32_16x16x16bf16_1k(A2[1], Bg1, D2, 0, 0, 0);

            // every row of D2 equals y[pos]; quad 0 lanes write their column
            if (quad == 0)
                yt[chunk * 64 + mf * 16 + l15][wave] = D2[0];
        }
    }
    __syncthreads();   // yt columns written by different waves

    // ---- coalesced output: float4 per thread ----
    int t = t0 + tid;
    if (t < TOUT) {
        float4 v = *(const float4*)yt[tid];
        *(float4*)&out[((size_t)(b * TOUT + t)) * NCH + ng * 4] = v;
    }
}

extern "C" void kernel_launch(void* const* d_in, const int* in_sizes, int n_in,
                              void* d_out, int out_size, void* d_ws, size_t ws_size,
                              hipStream_t stream)
{
    const float* X  = (const float*)d_in[0];
    const float* W0 = (const float*)d_in[1];
    const float* b0 = (const float*)d_in[2];
    const float* W1 = (const float*)d_in[3];
    const float* b1 = (const float*)d_in[4];
    const float* W2 = (const float*)d_in[5];
    const float* b2 = (const float*)d_in[6];
    float* out = (float*)d_out;

    unsigned short* W0b = (unsigned short*)d_ws;                    // 1,310,720 B
    unsigned short* W1b = (unsigned short*)((char*)d_ws + 1310720); //   131,072 B
    unsigned short* W2b = (unsigned short*)((char*)d_ws + 1441792); //     4,096 B

    prep_w<<<545, 256, 0, stream>>>(W0, W0b, W1, W1b, W2, W2b);
    mlp_mfma<<<dim3(128, 16), 256, 0, stream>>>(X, W0b, W1b, W2b, b0, b1, b2, out);
}